// Round 11
// baseline (460.072 us; speedup 1.0000x reference)
//
#include <hip/hip_runtime.h>
#include <math.h>

// InterRankAttention — R11: attn gets paired-rcp gelu (12 trans/edge, was 16) +
// dual independent online-softmax chains (2x ILP on the serial update path);
// gemm_hidden gets register-prefetch of the next B column during MFMA
// (hides L2 latency; launch_bounds(256,4) caps VGPR at 128).
// Kept from R10: persistent-A hidden GEMM with aliased LDS, bf16 H storage,
// exp2-domain attention, parallel CSR scan.

typedef __bf16 bf16x8 __attribute__((ext_vector_type(8)));
typedef float  f32x4  __attribute__((ext_vector_type(4)));
typedef float  f32x2  __attribute__((ext_vector_type(2)));

__device__ __forceinline__ unsigned short f2bf(float x) {
    unsigned u = __float_as_uint(x);
    u += 0x7FFFu + ((u >> 16) & 1u);   // round-to-nearest-even
    return (unsigned short)(u >> 16);
}
__device__ __forceinline__ float bf2f(unsigned short b) {
    return __uint_as_float(((unsigned)b) << 16);
}
__device__ __forceinline__ unsigned pack_tr(float a, float b) {
    return (__float_as_uint(a) >> 16) | (__float_as_uint(b) & 0xFFFF0000u);
}
__device__ __forceinline__ float res16(float x) {
    return x - __uint_as_float(__float_as_uint(x) & 0xFFFF0000u);
}
__device__ __forceinline__ unsigned short bf_rn(float x) {
    return (unsigned short)((__float_as_uint(x) + 0x8000u) >> 16);
}
__device__ __forceinline__ f32x2 up2(unsigned u) {
    f32x2 r;
    r.x = __uint_as_float(u << 16);
    r.y = __uint_as_float(u & 0xFFFF0000u);
    return r;
}
__device__ __forceinline__ float exp2_fast(float x) {
#if __has_builtin(__builtin_amdgcn_exp2f)
    return __builtin_amdgcn_exp2f(x);
#else
    return exp2f(x);
#endif
}

// gelu in exp2 domain with PAIRED reciprocal: one rcp per 2 elements.
// r.x = 1/(ex) computed as ey*rcp(ex*ey). Overflow-safe: if ex*ey=inf then
// rp=0 -> r=0 -> gelu=x, which is the correct large-x limit.
__device__ __forceinline__ f32x2 gelu2(f32x2 v) {
    f32x2 v2 = v * v;
    f32x2 u  = v * (v2 * 0.10294355f + 2.30220820f);
    float ex = exp2_fast(u.x) + 1.0f;
    float ey = exp2_fast(u.y) + 1.0f;
    float rp = __builtin_amdgcn_rcpf(ex * ey);
    f32x2 r;
    r.x = ey * rp;
    r.y = ex * rp;
    return v - v * r;
}

__device__ __forceinline__ float edge_logit(uint4 h,
    f32x2 ht0, f32x2 ht1, f32x2 ht2, f32x2 ht3,
    f32x2 aw0, f32x2 aw1, f32x2 aw2, f32x2 aw3) {
    f32x2 qv = gelu2(up2(h.x) + ht0) * aw0;
    qv += gelu2(up2(h.y) + ht1) * aw1;
    qv += gelu2(up2(h.z) + ht2) * aw2;
    qv += gelu2(up2(h.w) + ht3) * aw3;
    return qv.x + qv.y;
}

// ---------------- weight prep: WT_hi/WT_lo [1280][128] bf16 + bias_cat[640] ----------------
__global__ __launch_bounds__(128)
void prep_weights_kernel(const float* __restrict__ Ws, const float* __restrict__ Wm,
                         const float* __restrict__ Wt, const float* __restrict__ Wo,
                         const float* __restrict__ bs, const float* __restrict__ bm,
                         unsigned short* __restrict__ WThi, unsigned short* __restrict__ WTlo,
                         float* __restrict__ bias_cat) {
    int n = blockIdx.x, k = threadIdx.x;
    float w;
    if      (n < 512)  w = Ws[(size_t)k * 512 + n];
    else if (n < 640)  w = Wm[(size_t)k * 128 + (n - 512)];
    else if (n < 1152) w = Wt[(size_t)k * 512 + (n - 640)];
    else               w = Wo[(size_t)k * 128 + (n - 1152)];
    unsigned short hi = f2bf(w);
    WThi[(size_t)n * 128 + k] = hi;
    WTlo[(size_t)n * 128 + k] = f2bf(w - bf2f(hi));
    if (k == 0 && n < 640) bias_cat[n] = (n < 512) ? bs[n] : bm[n - 512];
}

// ---------------- CSR build ----------------
__global__ void hist_kernel(const int* __restrict__ tgt, int* __restrict__ counts, int E) {
    int e = blockIdx.x * blockDim.x + threadIdx.x;
    if (e < E) atomicAdd(&counts[tgt[e]], 1);
}

__global__ __launch_bounds__(256)
void scan_partial_kernel(const int* __restrict__ counts, int* __restrict__ partials, int M) {
    __shared__ int sdata[256];
    int b = blockIdx.x, tid = threadIdx.x;
    int base = b * 1024 + tid * 4;
    int s = 0;
#pragma unroll
    for (int k = 0; k < 4; ++k) { int idx = base + k; if (idx < M) s += counts[idx]; }
    sdata[tid] = s; __syncthreads();
    for (int d = 128; d > 0; d >>= 1) {
        if (tid < d) sdata[tid] += sdata[tid + d];
        __syncthreads();
    }
    if (tid == 0) partials[b] = sdata[0];
}

__global__ __launch_bounds__(64)
void scan_partials_kernel(const int* __restrict__ partials, int* __restrict__ pbase,
                          int* __restrict__ offsets, int P, int M) {
    int lane = threadIdx.x;
    int own = (lane < P) ? partials[lane] : 0;
    int v = own;
    for (int d = 1; d < 64; d <<= 1) {
        int o = __shfl_up(v, d);
        if (lane >= d) v += o;
    }
    if (lane < P) pbase[lane] = v - own;
    if (lane == 63) offsets[M] = v;
}

__global__ __launch_bounds__(256)
void scan_final_kernel(const int* __restrict__ counts, const int* __restrict__ pbase,
                       int* __restrict__ offsets, int M) {
    __shared__ int sdata[256];
    int b = blockIdx.x, tid = threadIdx.x;
    int base = b * 1024 + tid * 4;
    int c0 = 0, c1 = 0, c2 = 0, c3 = 0;
    if (base + 0 < M) c0 = counts[base + 0];
    if (base + 1 < M) c1 = counts[base + 1];
    if (base + 2 < M) c2 = counts[base + 2];
    if (base + 3 < M) c3 = counts[base + 3];
    int s = c0 + c1 + c2 + c3;
    sdata[tid] = s; __syncthreads();
    int v = s;
    for (int d = 1; d < 256; d <<= 1) {
        int o = (tid >= d) ? sdata[tid - d] : 0;
        __syncthreads();
        v += o;
        sdata[tid] = v;
        __syncthreads();
    }
    int ex = pbase[b] + v - s;
    if (base + 0 < M) offsets[base + 0] = ex;
    if (base + 1 < M) offsets[base + 1] = ex + c0;
    if (base + 2 < M) offsets[base + 2] = ex + c0 + c1;
    if (base + 3 < M) offsets[base + 3] = ex + c0 + c1 + c2;
}

__global__ void scatter_kernel(const int* __restrict__ tgt, const int* __restrict__ src,
                               const int* __restrict__ offsets,
                               int* __restrict__ cursor, int* __restrict__ srcs_sorted, int E) {
    int e = blockIdx.x * blockDim.x + threadIdx.x;
    if (e < E) {
        int t = tgt[e];
        int r = atomicAdd(&cursor[t], 1);
        srcs_sorted[offsets[t] + r] = src[e];
    }
}

// ---------------- persistent-A hidden GEMM, LDS-staged B with register prefetch ----------------
__global__ __launch_bounds__(256, 4)
void gemm_hidden_kernel(const float* __restrict__ src_f, const float* __restrict__ tgt_f,
                        const unsigned short* __restrict__ WThi, const unsigned short* __restrict__ WTlo,
                        const float* __restrict__ bias_cat, const float* __restrict__ bt,
                        unsigned short* __restrict__ Hs, unsigned short* __restrict__ Hm,
                        unsigned short* __restrict__ Ht, int N, int M, int nT0) {
    __shared__ unsigned short BufHi[64 * 136];   // A-hi, then aliased as B-hi per column
    __shared__ unsigned short BufLo[64 * 136];   // A-lo, then aliased as B-lo per column

    int bx = blockIdx.x;
    bool side1 = bx >= nT0;
    const float* Af = side1 ? tgt_f : src_f;
    int rows = side1 ? M : N;
    int row0 = (side1 ? bx - nT0 : bx) * 64;
    int nCols = side1 ? 8 : 10;
    int colWbase = side1 ? 640 : 0;
    const float* bias = side1 ? bt : bias_cat;

    int tid = threadIdx.x;

    // ---- stage A once: trunc-split hi/lo bf16
#pragma unroll
    for (int l = 0; l < 4; ++l) {
        int idx = l * 256 + tid;
        int r = idx >> 4, c8 = idx & 15;
        int row = row0 + r;
        float4 v0 = make_float4(0.f, 0.f, 0.f, 0.f), v1 = v0;
        if (row < rows) {
            v0 = *(const float4*)(Af + (size_t)row * 128 + c8 * 8);
            v1 = *(const float4*)(Af + (size_t)row * 128 + c8 * 8 + 4);
        }
        uint4 hp, lp;
        hp.x = pack_tr(v0.x, v0.y); hp.y = pack_tr(v0.z, v0.w);
        hp.z = pack_tr(v1.x, v1.y); hp.w = pack_tr(v1.z, v1.w);
        lp.x = pack_tr(res16(v0.x), res16(v0.y)); lp.y = pack_tr(res16(v0.z), res16(v0.w));
        lp.z = pack_tr(res16(v1.x), res16(v1.y)); lp.w = pack_tr(res16(v1.z), res16(v1.w));
        *(uint4*)(&BufHi[r * 136 + c8 * 8]) = hp;
        *(uint4*)(&BufLo[r * 136 + c8 * 8]) = lp;
    }
    __syncthreads();

    int wid = tid >> 6, lane = tid & 63;
    int wm = (wid >> 1) * 32, wn = (wid & 1) * 32;
    int g = lane >> 4, r16 = lane & 15;

    // ---- lift A fragments into registers (once): 64 VGPR
    bf16x8 Ah0[4], Ah1[4], Al0[4], Al1[4];
#pragma unroll
    for (int kk = 0; kk < 4; ++kk) {
        int k0 = kk * 32 + g * 8;
        Ah0[kk] = *(const bf16x8*)(&BufHi[(wm + r16) * 136 + k0]);
        Ah1[kk] = *(const bf16x8*)(&BufHi[(wm + 16 + r16) * 136 + k0]);
        Al0[kk] = *(const bf16x8*)(&BufLo[(wm + r16) * 136 + k0]);
        Al1[kk] = *(const bf16x8*)(&BufLo[(wm + 16 + r16) * 136 + k0]);
    }
    __syncthreads();   // A frags lifted; LDS reusable for B

    // ---- preload column 0 into registers (8 uint4/thread)
    uint4 pbh[4], pbl[4];
    {
        int colW = colWbase;
#pragma unroll
        for (int l = 0; l < 4; ++l) {
            int ci = l * 256 + tid;
            int r = ci >> 4, c8 = ci & 15;
            pbh[l] = *(const uint4*)(WThi + (size_t)(colW + r) * 128 + c8 * 8);
            pbl[l] = *(const uint4*)(WTlo + (size_t)(colW + r) * 128 + c8 * 8);
        }
    }

    for (int c = 0; c < nCols; ++c) {
        // write prefetched B to LDS
#pragma unroll
        for (int l = 0; l < 4; ++l) {
            int ci = l * 256 + tid;
            int r = ci >> 4, c8 = ci & 15;
            *(uint4*)(&BufHi[r * 136 + c8 * 8]) = pbh[l];
            *(uint4*)(&BufLo[r * 136 + c8 * 8]) = pbl[l];
        }
        __syncthreads();

        // issue next column's loads (consumed next iteration; latency hidden by MFMA)
        if (c + 1 < nCols) {
            int colW = colWbase + (c + 1) * 64;
#pragma unroll
            for (int l = 0; l < 4; ++l) {
                int ci = l * 256 + tid;
                int r = ci >> 4, c8 = ci & 15;
                pbh[l] = *(const uint4*)(WThi + (size_t)(colW + r) * 128 + c8 * 8);
                pbl[l] = *(const uint4*)(WTlo + (size_t)(colW + r) * 128 + c8 * 8);
            }
        }

        f32x4 acc00 = {0.f, 0.f, 0.f, 0.f}, acc01 = acc00, acc10 = acc00, acc11 = acc00;
#pragma unroll
        for (int kk = 0; kk < 4; ++kk) {
            int k0 = kk * 32 + g * 8;
            bf16x8 bh0 = *(const bf16x8*)(&BufHi[(wn + r16) * 136 + k0]);
            bf16x8 bh1 = *(const bf16x8*)(&BufHi[(wn + 16 + r16) * 136 + k0]);
            bf16x8 bl0 = *(const bf16x8*)(&BufLo[(wn + r16) * 136 + k0]);
            bf16x8 bl1 = *(const bf16x8*)(&BufLo[(wn + 16 + r16) * 136 + k0]);
            acc00 = __builtin_amdgcn_mfma_f32_16x16x32_bf16(Ah0[kk], bh0, acc00, 0, 0, 0);
            acc00 = __builtin_amdgcn_mfma_f32_16x16x32_bf16(Ah0[kk], bl0, acc00, 0, 0, 0);
            acc00 = __builtin_amdgcn_mfma_f32_16x16x32_bf16(Al0[kk], bh0, acc00, 0, 0, 0);
            acc01 = __builtin_amdgcn_mfma_f32_16x16x32_bf16(Ah0[kk], bh1, acc01, 0, 0, 0);
            acc01 = __builtin_amdgcn_mfma_f32_16x16x32_bf16(Ah0[kk], bl1, acc01, 0, 0, 0);
            acc01 = __builtin_amdgcn_mfma_f32_16x16x32_bf16(Al0[kk], bh1, acc01, 0, 0, 0);
            acc10 = __builtin_amdgcn_mfma_f32_16x16x32_bf16(Ah1[kk], bh0, acc10, 0, 0, 0);
            acc10 = __builtin_amdgcn_mfma_f32_16x16x32_bf16(Ah1[kk], bl0, acc10, 0, 0, 0);
            acc10 = __builtin_amdgcn_mfma_f32_16x16x32_bf16(Al1[kk], bh0, acc10, 0, 0, 0);
            acc11 = __builtin_amdgcn_mfma_f32_16x16x32_bf16(Ah1[kk], bh1, acc11, 0, 0, 0);
            acc11 = __builtin_amdgcn_mfma_f32_16x16x32_bf16(Ah1[kk], bl1, acc11, 0, 0, 0);
            acc11 = __builtin_amdgcn_mfma_f32_16x16x32_bf16(Al1[kk], bh1, acc11, 0, 0, 0);
        }

        int c0 = c * 64 + wn + r16;
        int c1 = c0 + 16;
        float bv0 = bias[c0], bv1 = bias[c1];
        unsigned short* out; int stride, oc0, oc1;
        if (side1)        { out = Ht; stride = 512; oc0 = c0;       oc1 = c1; }
        else if (c0 < 512){ out = Hs; stride = 512; oc0 = c0;       oc1 = c1; }
        else              { out = Hm; stride = 128; oc0 = c0 - 512; oc1 = c1 - 512; }
#pragma unroll
        for (int ii = 0; ii < 4; ++ii) {
            int rA = row0 + wm + g * 4 + ii;
            int rB = rA + 16;
            if (rA < rows) {
                out[(size_t)rA * stride + oc0] = bf_rn(acc00[ii] + bv0);
                out[(size_t)rA * stride + oc1] = bf_rn(acc01[ii] + bv1);
            }
            if (rB < rows) {
                out[(size_t)rB * stride + oc0] = bf_rn(acc10[ii] + bv0);
                out[(size_t)rB * stride + oc1] = bf_rn(acc11[ii] + bv1);
            }
        }
        __syncthreads();
    }
}

// ---------------- output GEMM: out[M x 128] f32 = agg(bf16) @ Wo_hi + bo ----------------
__global__ __launch_bounds__(256, 4)
void gemm_out_kernel(const unsigned short* __restrict__ A,
                     const unsigned short* __restrict__ BT,
                     const float* __restrict__ bias,
                     float* __restrict__ C, int Mrows, int Ntot) {
    __shared__ unsigned short As[64 * 136];
    __shared__ unsigned short Bs[64 * 136];
    int tid = threadIdx.x;
    int row0 = blockIdx.y * 64, col0 = blockIdx.x * 64;

#pragma unroll
    for (int l = 0; l < 4; ++l) {
        int idx = l * 256 + tid;
        int r = idx >> 4, c8 = idx & 15;
        int row = row0 + r;
        uint4 v = make_uint4(0, 0, 0, 0);
        if (row < Mrows) v = *(const uint4*)(A + (size_t)row * 128 + c8 * 8);
        *(uint4*)(&As[r * 136 + c8 * 8]) = v;
    }
#pragma unroll
    for (int l = 0; l < 4; ++l) {
        int idx = l * 256 + tid;
        int r = idx >> 4, c8 = idx & 15;
        uint4 v = *(const uint4*)(BT + (size_t)(col0 + r) * 128 + c8 * 8);
        *(uint4*)(&Bs[r * 136 + c8 * 8]) = v;
    }
    __syncthreads();

    int wid = tid >> 6, lane = tid & 63;
    int wm = (wid >> 1) * 32, wn = (wid & 1) * 32;
    int g = lane >> 4, r16 = lane & 15;

    f32x4 acc00 = {0.f, 0.f, 0.f, 0.f}, acc01 = acc00, acc10 = acc00, acc11 = acc00;

#pragma unroll
    for (int kk = 0; kk < 4; ++kk) {
        int k0 = kk * 32 + g * 8;
        bf16x8 a0 = *(const bf16x8*)(&As[(wm + r16) * 136 + k0]);
        bf16x8 a1 = *(const bf16x8*)(&As[(wm + 16 + r16) * 136 + k0]);
        bf16x8 b0 = *(const bf16x8*)(&Bs[(wn + r16) * 136 + k0]);
        bf16x8 b1 = *(const bf16x8*)(&Bs[(wn + 16 + r16) * 136 + k0]);
        acc00 = __builtin_amdgcn_mfma_f32_16x16x32_bf16(a0, b0, acc00, 0, 0, 0);
        acc01 = __builtin_amdgcn_mfma_f32_16x16x32_bf16(a0, b1, acc01, 0, 0, 0);
        acc10 = __builtin_amdgcn_mfma_f32_16x16x32_bf16(a1, b0, acc10, 0, 0, 0);
        acc11 = __builtin_amdgcn_mfma_f32_16x16x32_bf16(a1, b1, acc11, 0, 0, 0);
    }

    float bv0 = bias[col0 + wn + r16];
    float bv1 = bias[col0 + wn + 16 + r16];
#pragma unroll
    for (int i = 0; i < 4; ++i) {
        int rA = row0 + wm + g * 4 + i;
        int rB = rA + 16;
        if (rA < Mrows) {
            C[(size_t)rA * Ntot + col0 + wn + r16]      = acc00[i] + bv0;
            C[(size_t)rA * Ntot + col0 + wn + 16 + r16] = acc01[i] + bv1;
        }
        if (rB < Mrows) {
            C[(size_t)rB * Ntot + col0 + wn + r16]      = acc10[i] + bv0;
            C[(size_t)rB * Ntot + col0 + wn + 16 + r16] = acc11[i] + bv1;
        }
    }
}

// ---------------- fused per-target online-softmax attention + aggregation ----------------
// One wave per target, 4-edge groups with prefetch; TWO independent softmax
// chains (edges i,i+1 -> chain0; i+2,i+3 -> chain1) merged at the end.
__global__ __launch_bounds__(256)
void attn_kernel(const unsigned short* __restrict__ Hs, const unsigned short* __restrict__ Ht,
                 const unsigned short* __restrict__ Hm, const float* __restrict__ attn_w,
                 const int* __restrict__ offsets, const int* __restrict__ srcs,
                 unsigned short* __restrict__ agg, int M) {
    int wave = threadIdx.x >> 6;
    int lane = threadIdx.x & 63;
    int t = blockIdx.x * 4 + wave;
    if (t >= M) return;

    int j0 = lane << 3;
    uint4 h = *(const uint4*)(Ht + (size_t)t * 512 + j0);
    f32x2 ht0 = up2(h.x), ht1 = up2(h.y), ht2 = up2(h.z), ht3 = up2(h.w);
    const float L2E = 1.4426950408889634f;
    float4 a0 = *(const float4*)(attn_w + j0);
    float4 a1 = *(const float4*)(attn_w + j0 + 4);
    f32x2 aw0 = {a0.x * L2E, a0.y * L2E};
    f32x2 aw1 = {a0.z * L2E, a0.w * L2E};
    f32x2 aw2 = {a1.x * L2E, a1.y * L2E};
    f32x2 aw3 = {a1.z * L2E, a1.w * L2E};

    int off = offsets[t];
    int end = offsets[t + 1];
    int hm_off = lane << 1;

    float m0 = -INFINITY, m1 = -INFINITY, den0 = 0.f, den1 = 0.f;
    f32x2 ac0 = {0.f, 0.f}, ac1 = {0.f, 0.f};

    int i = off;
    uint4 hA, hB, hC, hD;
    unsigned mA, mB, mC, mD;
    bool have = (end - i) >= 4;
    if (have) {
        int s0 = srcs[i], s1 = srcs[i + 1], s2 = srcs[i + 2], s3 = srcs[i + 3];
        hA = *(const uint4*)(Hs + (size_t)s0 * 512 + j0);
        hB = *(const uint4*)(Hs + (size_t)s1 * 512 + j0);
        hC = *(const uint4*)(Hs + (size_t)s2 * 512 + j0);
        hD = *(const uint4*)(Hs + (size_t)s3 * 512 + j0);
        mA = *(const unsigned*)(Hm + (size_t)s0 * 128 + hm_off);
        mB = *(const unsigned*)(Hm + (size_t)s1 * 128 + hm_off);
        mC = *(const unsigned*)(Hm + (size_t)s2 * 128 + hm_off);
        mD = *(const unsigned*)(Hm + (size_t)s3 * 128 + hm_off);
    }
    while (have) {
        int ni = i + 4;
        bool nhave = (end - ni) >= 4;
        uint4 nhA, nhB, nhC, nhD;
        unsigned nmA, nmB, nmC, nmD;
        if (nhave) {
            int s0 = srcs[ni], s1 = srcs[ni + 1], s2 = srcs[ni + 2], s3 = srcs[ni + 3];
            nhA = *(const uint4*)(Hs + (size_t)s0 * 512 + j0);
            nhB = *(const uint4*)(Hs + (size_t)s1 * 512 + j0);
            nhC = *(const uint4*)(Hs + (size_t)s2 * 512 + j0);
            nhD = *(const uint4*)(Hs + (size_t)s3 * 512 + j0);
            nmA = *(const unsigned*)(Hm + (size_t)s0 * 128 + hm_off);
            nmB = *(const unsigned*)(Hm + (size_t)s1 * 128 + hm_off);
            nmC = *(const unsigned*)(Hm + (size_t)s2 * 128 + hm_off);
            nmD = *(const unsigned*)(Hm + (size_t)s3 * 128 + hm_off);
        }

        float q0 = edge_logit(hA, ht0, ht1, ht2, ht3, aw0, aw1, aw2, aw3);
        float q1 = edge_logit(hB, ht0, ht1, ht2, ht3, aw0, aw1, aw2, aw3);
        float q2 = edge_logit(hC, ht0, ht1, ht2, ht3, aw0, aw1, aw2, aw3);
        float q3 = edge_logit(hD, ht0, ht1, ht2, ht3, aw0, aw1, aw2, aw3);
        q0 += __shfl_xor(q0, 1); q1 += __shfl_xor(q1, 1); q2 += __shfl_xor(q2, 1); q3 += __shfl_xor(q3, 1);
        q0 += __shfl_xor(q0, 2); q1 += __shfl_xor(q1, 2); q2 += __shfl_xor(q2, 2); q3 += __shfl_xor(q3, 2);
        q0 += __shfl_xor(q0, 4); q1 += __shfl_xor(q1, 4); q2 += __shfl_xor(q2, 4); q3 += __shfl_xor(q3, 4);
        q0 += __shfl_xor(q0, 8); q1 += __shfl_xor(q1, 8); q2 += __shfl_xor(q2, 8); q3 += __shfl_xor(q3, 8);

        // chain0: q0,q1
        float n0 = fmaxf(m0, fmaxf(q0, q1));
        float s0c = exp2_fast(m0 - n0);
        float p0 = exp2_fast(q0 - n0);
        float p1 = exp2_fast(q1 - n0);
        den0 = fmaf(den0, s0c, p0 + p1);
        ac0 = ac0 * s0c;
        ac0 += p0 * up2(mA);
        ac0 += p1 * up2(mB);
        m0 = n0;
        // chain1: q2,q3
        float n1 = fmaxf(m1, fmaxf(q2, q3));
        float s1c = exp2_fast(m1 - n1);
        float p2 = exp2_fast(q2 - n1);
        float p3 = exp2_fast(q3 - n1);
        den1 = fmaf(den1, s1c, p2 + p3);
        ac1 = ac1 * s1c;
        ac1 += p2 * up2(mC);
        ac1 += p3 * up2(mD);
        m1 = n1;

        i = ni;
        if (nhave) {
            hA = nhA; hB = nhB; hC = nhC; hD = nhD;
            mA = nmA; mB = nmB; mC = nmC; mD = nmD;
        }
        have = nhave;
    }
    // merge chain1 into chain0 (chain1 only ran if at least one full 4-group)
    if (m1 != -INFINITY) {
        float mm = fmaxf(m0, m1);
        float s0c = exp2_fast(m0 - mm);
        float s1c = exp2_fast(m1 - mm);
        den0 = den0 * s0c + den1 * s1c;
        ac0 = ac0 * s0c + ac1 * s1c;
        m0 = mm;
    }
    // tail (0..3 edges) on chain0
    for (; i < end; ++i) {
        int s0 = srcs[i];
        uint4 hX = *(const uint4*)(Hs + (size_t)s0 * 512 + j0);
        unsigned mX = *(const unsigned*)(Hm + (size_t)s0 * 128 + hm_off);
        float q0 = edge_logit(hX, ht0, ht1, ht2, ht3, aw0, aw1, aw2, aw3);
        q0 += __shfl_xor(q0, 1);
        q0 += __shfl_xor(q0, 2);
        q0 += __shfl_xor(q0, 4);
        q0 += __shfl_xor(q0, 8);
        float nm = fmaxf(m0, q0);
        float sc = exp2_fast(m0 - nm);
        float p0 = exp2_fast(q0 - nm);
        den0 = fmaf(den0, sc, p0);
        ac0 = ac0 * sc + p0 * up2(mX);
        m0 = nm;
    }
    float r = (end > off) ? __builtin_amdgcn_rcpf(den0) : 0.0f;
    ushort2 o;
    o.x = f2bf(ac0.x * r);
    o.y = f2bf(ac0.y * r);
    *(ushort2*)(agg + (size_t)t * 128 + hm_off) = o;
}

extern "C" void kernel_launch(void* const* d_in, const int* in_sizes, int n_in,
                              void* d_out, int out_size, void* d_ws, size_t ws_size,
                              hipStream_t stream) {
    const float* src_f  = (const float*)d_in[0];
    const float* tgt_f  = (const float*)d_in[1];
    const int*   e_tgt  = (const int*)d_in[2];
    const int*   e_src  = (const int*)d_in[3];
    const float* Ws     = (const float*)d_in[4];
    const float* bs     = (const float*)d_in[5];
    const float* Wt     = (const float*)d_in[6];
    const float* bt     = (const float*)d_in[7];
    const float* attn_w = (const float*)d_in[8];
    const float* Wm     = (const float*)d_in[9];
    const float* bm     = (const float*)d_in[10];
    const float* Wo     = (const float*)d_in[11];
    const float* bo     = (const float*)d_in[12];

    int N = in_sizes[0] / 128;
    int M = in_sizes[1] / 128;
    int E = in_sizes[2];

    char* ws = (char*)d_ws;
    size_t woff = 0;
    auto alloc = [&](size_t bytes) -> void* {
        void* p = ws + woff;
        woff += ((bytes + 255) / 256) * 256;
        return p;
    };
    unsigned short* Hs       = (unsigned short*)alloc((size_t)N * 512 * 2);
    unsigned short* Ht       = (unsigned short*)alloc((size_t)M * 512 * 2);
    unsigned short* Hm       = (unsigned short*)alloc((size_t)N * 128 * 2);
    unsigned short* agg_bf   = (unsigned short*)alloc((size_t)M * 128 * 2);
    unsigned short* WThi     = (unsigned short*)alloc((size_t)1280 * 128 * 2);
    unsigned short* WTlo     = (unsigned short*)alloc((size_t)1280 * 128 * 2);
    float*          bias_cat = (float*)alloc(640 * 4);
    int*            counts   = (int*)alloc((size_t)2 * M * 4);   // counts | cursor
    int*            cursor   = counts + M;
    int*            offsets  = (int*)alloc((size_t)(M + 1) * 4);
    int*            srcs     = (int*)alloc((size_t)E * 4);
    int*            partials = (int*)alloc(64 * 4);
    int*            pbase    = (int*)alloc(64 * 4);

    hipMemsetAsync(counts, 0, (size_t)2 * M * 4, stream);

    const int tb = 256;
    int P = (M + 1023) / 1024;

    // CSR build
    hist_kernel<<<(E + tb - 1) / tb, tb, 0, stream>>>(e_tgt, counts, E);
    scan_partial_kernel<<<P, 256, 0, stream>>>(counts, partials, M);
    scan_partials_kernel<<<1, 64, 0, stream>>>(partials, pbase, offsets, P, M);
    scan_final_kernel<<<P, 256, 0, stream>>>(counts, pbase, offsets, M);
    scatter_kernel<<<(E + tb - 1) / tb, tb, 0, stream>>>(e_tgt, e_src, offsets, cursor, srcs, E);

    // Weight prep
    prep_weights_kernel<<<1280, 128, 0, stream>>>(Ws, Wm, Wt, Wo, bs, bm, WThi, WTlo, bias_cat);

    // Persistent-A merged hidden GEMMs (LDS-staged B, register prefetch)
    int nT0 = (N + 63) / 64, nT1 = (M + 63) / 64;
    gemm_hidden_kernel<<<nT0 + nT1, 256, 0, stream>>>(src_f, tgt_f, WThi, WTlo,
                                                      bias_cat, bt, Hs, Hm, Ht, N, M, nT0);

    attn_kernel<<<(M + 3) / 4, 256, 0, stream>>>(Hs, Ht, Hm, attn_w, offsets, srcs, agg_bf, M);

    // out = agg @ Wo + bo
    dim3 go(128 / 64, (M + 63) / 64);
    gemm_out_kernel<<<go, 256, 0, stream>>>(agg_bf, WThi + (size_t)1152 * 128, bo,
                                            (float*)d_out, M, 128);
}

// Round 12
// 331.369 us; speedup vs baseline: 1.3884x; 1.3884x over previous
//
#include <hip/hip_runtime.h>
#include <math.h>

// InterRankAttention — R12: revert R11's gemm register-prefetch (it spilled:
// WRITE_SIZE 112->560MB, MfmaUtil 8%). gemm_hidden restored to R10's proven
// persistent-A + LDS-staged-B form (launch_bounds(256,3), no spill).
// Kept from R11: attn paired-rcp gelu (12 trans/edge) + dual softmax chains.

typedef __bf16 bf16x8 __attribute__((ext_vector_type(8)));
typedef float  f32x4  __attribute__((ext_vector_type(4)));
typedef float  f32x2  __attribute__((ext_vector_type(2)));

__device__ __forceinline__ unsigned short f2bf(float x) {
    unsigned u = __float_as_uint(x);
    u += 0x7FFFu + ((u >> 16) & 1u);   // round-to-nearest-even
    return (unsigned short)(u >> 16);
}
__device__ __forceinline__ float bf2f(unsigned short b) {
    return __uint_as_float(((unsigned)b) << 16);
}
__device__ __forceinline__ unsigned pack_tr(float a, float b) {
    return (__float_as_uint(a) >> 16) | (__float_as_uint(b) & 0xFFFF0000u);
}
__device__ __forceinline__ float res16(float x) {
    return x - __uint_as_float(__float_as_uint(x) & 0xFFFF0000u);
}
__device__ __forceinline__ unsigned short bf_rn(float x) {
    return (unsigned short)((__float_as_uint(x) + 0x8000u) >> 16);
}
__device__ __forceinline__ f32x2 up2(unsigned u) {
    f32x2 r;
    r.x = __uint_as_float(u << 16);
    r.y = __uint_as_float(u & 0xFFFF0000u);
    return r;
}
__device__ __forceinline__ float exp2_fast(float x) {
#if __has_builtin(__builtin_amdgcn_exp2f)
    return __builtin_amdgcn_exp2f(x);
#else
    return exp2f(x);
#endif
}

// gelu in exp2 domain with PAIRED reciprocal: one rcp per 2 elements.
// Overflow-safe: ex*ey=inf -> rp=0 -> gelu=x (correct large-x limit).
__device__ __forceinline__ f32x2 gelu2(f32x2 v) {
    f32x2 v2 = v * v;
    f32x2 u  = v * (v2 * 0.10294355f + 2.30220820f);
    float ex = exp2_fast(u.x) + 1.0f;
    float ey = exp2_fast(u.y) + 1.0f;
    float rp = __builtin_amdgcn_rcpf(ex * ey);
    f32x2 r;
    r.x = ey * rp;
    r.y = ex * rp;
    return v - v * r;
}

__device__ __forceinline__ float edge_logit(uint4 h,
    f32x2 ht0, f32x2 ht1, f32x2 ht2, f32x2 ht3,
    f32x2 aw0, f32x2 aw1, f32x2 aw2, f32x2 aw3) {
    f32x2 qv = gelu2(up2(h.x) + ht0) * aw0;
    qv += gelu2(up2(h.y) + ht1) * aw1;
    qv += gelu2(up2(h.z) + ht2) * aw2;
    qv += gelu2(up2(h.w) + ht3) * aw3;
    return qv.x + qv.y;
}

// ---------------- weight prep: WT_hi/WT_lo [1280][128] bf16 + bias_cat[640] ----------------
__global__ __launch_bounds__(128)
void prep_weights_kernel(const float* __restrict__ Ws, const float* __restrict__ Wm,
                         const float* __restrict__ Wt, const float* __restrict__ Wo,
                         const float* __restrict__ bs, const float* __restrict__ bm,
                         unsigned short* __restrict__ WThi, unsigned short* __restrict__ WTlo,
                         float* __restrict__ bias_cat) {
    int n = blockIdx.x, k = threadIdx.x;
    float w;
    if      (n < 512)  w = Ws[(size_t)k * 512 + n];
    else if (n < 640)  w = Wm[(size_t)k * 128 + (n - 512)];
    else if (n < 1152) w = Wt[(size_t)k * 512 + (n - 640)];
    else               w = Wo[(size_t)k * 128 + (n - 1152)];
    unsigned short hi = f2bf(w);
    WThi[(size_t)n * 128 + k] = hi;
    WTlo[(size_t)n * 128 + k] = f2bf(w - bf2f(hi));
    if (k == 0 && n < 640) bias_cat[n] = (n < 512) ? bs[n] : bm[n - 512];
}

// ---------------- CSR build ----------------
__global__ void hist_kernel(const int* __restrict__ tgt, int* __restrict__ counts, int E) {
    int e = blockIdx.x * blockDim.x + threadIdx.x;
    if (e < E) atomicAdd(&counts[tgt[e]], 1);
}

__global__ __launch_bounds__(256)
void scan_partial_kernel(const int* __restrict__ counts, int* __restrict__ partials, int M) {
    __shared__ int sdata[256];
    int b = blockIdx.x, tid = threadIdx.x;
    int base = b * 1024 + tid * 4;
    int s = 0;
#pragma unroll
    for (int k = 0; k < 4; ++k) { int idx = base + k; if (idx < M) s += counts[idx]; }
    sdata[tid] = s; __syncthreads();
    for (int d = 128; d > 0; d >>= 1) {
        if (tid < d) sdata[tid] += sdata[tid + d];
        __syncthreads();
    }
    if (tid == 0) partials[b] = sdata[0];
}

__global__ __launch_bounds__(64)
void scan_partials_kernel(const int* __restrict__ partials, int* __restrict__ pbase,
                          int* __restrict__ offsets, int P, int M) {
    int lane = threadIdx.x;
    int own = (lane < P) ? partials[lane] : 0;
    int v = own;
    for (int d = 1; d < 64; d <<= 1) {
        int o = __shfl_up(v, d);
        if (lane >= d) v += o;
    }
    if (lane < P) pbase[lane] = v - own;
    if (lane == 63) offsets[M] = v;
}

__global__ __launch_bounds__(256)
void scan_final_kernel(const int* __restrict__ counts, const int* __restrict__ pbase,
                       int* __restrict__ offsets, int M) {
    __shared__ int sdata[256];
    int b = blockIdx.x, tid = threadIdx.x;
    int base = b * 1024 + tid * 4;
    int c0 = 0, c1 = 0, c2 = 0, c3 = 0;
    if (base + 0 < M) c0 = counts[base + 0];
    if (base + 1 < M) c1 = counts[base + 1];
    if (base + 2 < M) c2 = counts[base + 2];
    if (base + 3 < M) c3 = counts[base + 3];
    int s = c0 + c1 + c2 + c3;
    sdata[tid] = s; __syncthreads();
    int v = s;
    for (int d = 1; d < 256; d <<= 1) {
        int o = (tid >= d) ? sdata[tid - d] : 0;
        __syncthreads();
        v += o;
        sdata[tid] = v;
        __syncthreads();
    }
    int ex = pbase[b] + v - s;
    if (base + 0 < M) offsets[base + 0] = ex;
    if (base + 1 < M) offsets[base + 1] = ex + c0;
    if (base + 2 < M) offsets[base + 2] = ex + c0 + c1;
    if (base + 3 < M) offsets[base + 3] = ex + c0 + c1 + c2;
}

__global__ void scatter_kernel(const int* __restrict__ tgt, const int* __restrict__ src,
                               const int* __restrict__ offsets,
                               int* __restrict__ cursor, int* __restrict__ srcs_sorted, int E) {
    int e = blockIdx.x * blockDim.x + threadIdx.x;
    if (e < E) {
        int t = tgt[e];
        int r = atomicAdd(&cursor[t], 1);
        srcs_sorted[offsets[t] + r] = src[e];
    }
}

// ---------------- persistent-A hidden GEMM, LDS-staged B (R10 form) ----------------
__global__ __launch_bounds__(256, 3)
void gemm_hidden_kernel(const float* __restrict__ src_f, const float* __restrict__ tgt_f,
                        const unsigned short* __restrict__ WThi, const unsigned short* __restrict__ WTlo,
                        const float* __restrict__ bias_cat, const float* __restrict__ bt,
                        unsigned short* __restrict__ Hs, unsigned short* __restrict__ Hm,
                        unsigned short* __restrict__ Ht, int N, int M, int nT0) {
    __shared__ unsigned short BufHi[64 * 136];   // A-hi, then aliased as B-hi per column
    __shared__ unsigned short BufLo[64 * 136];   // A-lo, then aliased as B-lo per column

    int bx = blockIdx.x;
    bool side1 = bx >= nT0;
    const float* Af = side1 ? tgt_f : src_f;
    int rows = side1 ? M : N;
    int row0 = (side1 ? bx - nT0 : bx) * 64;
    int nCols = side1 ? 8 : 10;
    int colWbase = side1 ? 640 : 0;
    const float* bias = side1 ? bt : bias_cat;

    int tid = threadIdx.x;

    // ---- stage A once: 64 rows x 128 f32 -> trunc-split hi/lo bf16
#pragma unroll
    for (int l = 0; l < 4; ++l) {
        int idx = l * 256 + tid;
        int r = idx >> 4, c8 = idx & 15;
        int row = row0 + r;
        float4 v0 = make_float4(0.f, 0.f, 0.f, 0.f), v1 = v0;
        if (row < rows) {
            v0 = *(const float4*)(Af + (size_t)row * 128 + c8 * 8);
            v1 = *(const float4*)(Af + (size_t)row * 128 + c8 * 8 + 4);
        }
        uint4 hp, lp;
        hp.x = pack_tr(v0.x, v0.y); hp.y = pack_tr(v0.z, v0.w);
        hp.z = pack_tr(v1.x, v1.y); hp.w = pack_tr(v1.z, v1.w);
        lp.x = pack_tr(res16(v0.x), res16(v0.y)); lp.y = pack_tr(res16(v0.z), res16(v0.w));
        lp.z = pack_tr(res16(v1.x), res16(v1.y)); lp.w = pack_tr(res16(v1.z), res16(v1.w));
        *(uint4*)(&BufHi[r * 136 + c8 * 8]) = hp;
        *(uint4*)(&BufLo[r * 136 + c8 * 8]) = lp;
    }
    __syncthreads();

    int wid = tid >> 6, lane = tid & 63;
    int wm = (wid >> 1) * 32, wn = (wid & 1) * 32;
    int g = lane >> 4, r16 = lane & 15;

    // ---- lift A fragments into registers (once): 64 VGPR
    bf16x8 Ah0[4], Ah1[4], Al0[4], Al1[4];
#pragma unroll
    for (int kk = 0; kk < 4; ++kk) {
        int k0 = kk * 32 + g * 8;
        Ah0[kk] = *(const bf16x8*)(&BufHi[(wm + r16) * 136 + k0]);
        Ah1[kk] = *(const bf16x8*)(&BufHi[(wm + 16 + r16) * 136 + k0]);
        Al0[kk] = *(const bf16x8*)(&BufLo[(wm + r16) * 136 + k0]);
        Al1[kk] = *(const bf16x8*)(&BufLo[(wm + 16 + r16) * 136 + k0]);
    }
    __syncthreads();   // A frags lifted; LDS now reusable for B

    // ---- column loop: cooperative coalesced B staging into aliased LDS
    for (int c = 0; c < nCols; ++c) {
        int colW = colWbase + c * 64;
#pragma unroll
        for (int l = 0; l < 4; ++l) {
            int ci = l * 256 + tid;          // 1024 chunks of 8 shorts
            int r = ci >> 4, c8 = ci & 15;
            uint4 vh = *(const uint4*)(WThi + (size_t)(colW + r) * 128 + c8 * 8);
            uint4 vl = *(const uint4*)(WTlo + (size_t)(colW + r) * 128 + c8 * 8);
            *(uint4*)(&BufHi[r * 136 + c8 * 8]) = vh;
            *(uint4*)(&BufLo[r * 136 + c8 * 8]) = vl;
        }
        __syncthreads();

        f32x4 acc00 = {0.f, 0.f, 0.f, 0.f}, acc01 = acc00, acc10 = acc00, acc11 = acc00;
#pragma unroll
        for (int kk = 0; kk < 4; ++kk) {
            int k0 = kk * 32 + g * 8;
            bf16x8 bh0 = *(const bf16x8*)(&BufHi[(wn + r16) * 136 + k0]);
            bf16x8 bh1 = *(const bf16x8*)(&BufHi[(wn + 16 + r16) * 136 + k0]);
            bf16x8 bl0 = *(const bf16x8*)(&BufLo[(wn + r16) * 136 + k0]);
            bf16x8 bl1 = *(const bf16x8*)(&BufLo[(wn + 16 + r16) * 136 + k0]);
            acc00 = __builtin_amdgcn_mfma_f32_16x16x32_bf16(Ah0[kk], bh0, acc00, 0, 0, 0);
            acc00 = __builtin_amdgcn_mfma_f32_16x16x32_bf16(Ah0[kk], bl0, acc00, 0, 0, 0);
            acc00 = __builtin_amdgcn_mfma_f32_16x16x32_bf16(Al0[kk], bh0, acc00, 0, 0, 0);
            acc01 = __builtin_amdgcn_mfma_f32_16x16x32_bf16(Ah0[kk], bh1, acc01, 0, 0, 0);
            acc01 = __builtin_amdgcn_mfma_f32_16x16x32_bf16(Ah0[kk], bl1, acc01, 0, 0, 0);
            acc01 = __builtin_amdgcn_mfma_f32_16x16x32_bf16(Al0[kk], bh1, acc01, 0, 0, 0);
            acc10 = __builtin_amdgcn_mfma_f32_16x16x32_bf16(Ah1[kk], bh0, acc10, 0, 0, 0);
            acc10 = __builtin_amdgcn_mfma_f32_16x16x32_bf16(Ah1[kk], bl0, acc10, 0, 0, 0);
            acc10 = __builtin_amdgcn_mfma_f32_16x16x32_bf16(Al1[kk], bh0, acc10, 0, 0, 0);
            acc11 = __builtin_amdgcn_mfma_f32_16x16x32_bf16(Ah1[kk], bh1, acc11, 0, 0, 0);
            acc11 = __builtin_amdgcn_mfma_f32_16x16x32_bf16(Ah1[kk], bl1, acc11, 0, 0, 0);
            acc11 = __builtin_amdgcn_mfma_f32_16x16x32_bf16(Al1[kk], bh1, acc11, 0, 0, 0);
        }

        // epilogue: C/D layout col = lane&15, row = (lane>>4)*4 + reg
        int c0 = c * 64 + wn + r16;
        int c1 = c0 + 16;
        float bv0 = bias[c0], bv1 = bias[c1];
        unsigned short* out; int stride, oc0, oc1;
        if (side1)        { out = Ht; stride = 512; oc0 = c0;       oc1 = c1; }
        else if (c0 < 512){ out = Hs; stride = 512; oc0 = c0;       oc1 = c1; }
        else              { out = Hm; stride = 128; oc0 = c0 - 512; oc1 = c1 - 512; }
#pragma unroll
        for (int ii = 0; ii < 4; ++ii) {
            int rA = row0 + wm + g * 4 + ii;
            int rB = rA + 16;
            if (rA < rows) {
                out[(size_t)rA * stride + oc0] = bf_rn(acc00[ii] + bv0);
                out[(size_t)rA * stride + oc1] = bf_rn(acc01[ii] + bv1);
            }
            if (rB < rows) {
                out[(size_t)rB * stride + oc0] = bf_rn(acc10[ii] + bv0);
                out[(size_t)rB * stride + oc1] = bf_rn(acc11[ii] + bv1);
            }
        }
        __syncthreads();   // protect LDS before next column's staging
    }
}

// ---------------- output GEMM: out[M x 128] f32 = agg(bf16) @ Wo_hi + bo ----------------
__global__ __launch_bounds__(256, 4)
void gemm_out_kernel(const unsigned short* __restrict__ A,
                     const unsigned short* __restrict__ BT,
                     const float* __restrict__ bias,
                     float* __restrict__ C, int Mrows, int Ntot) {
    __shared__ unsigned short As[64 * 136];
    __shared__ unsigned short Bs[64 * 136];
    int tid = threadIdx.x;
    int row0 = blockIdx.y * 64, col0 = blockIdx.x * 64;

#pragma unroll
    for (int l = 0; l < 4; ++l) {
        int idx = l * 256 + tid;
        int r = idx >> 4, c8 = idx & 15;
        int row = row0 + r;
        uint4 v = make_uint4(0, 0, 0, 0);
        if (row < Mrows) v = *(const uint4*)(A + (size_t)row * 128 + c8 * 8);
        *(uint4*)(&As[r * 136 + c8 * 8]) = v;
    }
#pragma unroll
    for (int l = 0; l < 4; ++l) {
        int idx = l * 256 + tid;
        int r = idx >> 4, c8 = idx & 15;
        uint4 v = *(const uint4*)(BT + (size_t)(col0 + r) * 128 + c8 * 8);
        *(uint4*)(&Bs[r * 136 + c8 * 8]) = v;
    }
    __syncthreads();

    int wid = tid >> 6, lane = tid & 63;
    int wm = (wid >> 1) * 32, wn = (wid & 1) * 32;
    int g = lane >> 4, r16 = lane & 15;

    f32x4 acc00 = {0.f, 0.f, 0.f, 0.f}, acc01 = acc00, acc10 = acc00, acc11 = acc00;

#pragma unroll
    for (int kk = 0; kk < 4; ++kk) {
        int k0 = kk * 32 + g * 8;
        bf16x8 a0 = *(const bf16x8*)(&As[(wm + r16) * 136 + k0]);
        bf16x8 a1 = *(const bf16x8*)(&As[(wm + 16 + r16) * 136 + k0]);
        bf16x8 b0 = *(const bf16x8*)(&Bs[(wn + r16) * 136 + k0]);
        bf16x8 b1 = *(const bf16x8*)(&Bs[(wn + 16 + r16) * 136 + k0]);
        acc00 = __builtin_amdgcn_mfma_f32_16x16x32_bf16(a0, b0, acc00, 0, 0, 0);
        acc01 = __builtin_amdgcn_mfma_f32_16x16x32_bf16(a0, b1, acc01, 0, 0, 0);
        acc10 = __builtin_amdgcn_mfma_f32_16x16x32_bf16(a1, b0, acc10, 0, 0, 0);
        acc11 = __builtin_amdgcn_mfma_f32_16x16x32_bf16(a1, b1, acc11, 0, 0, 0);
    }

    float bv0 = bias[col0 + wn + r16];
    float bv1 = bias[col0 + wn + 16 + r16];
#pragma unroll
    for (int i = 0; i < 4; ++i) {
        int rA = row0 + wm + g * 4 + i;
        int rB = rA + 16;
        if (rA < Mrows) {
            C[(size_t)rA * Ntot + col0 + wn + r16]      = acc00[i] + bv0;
            C[(size_t)rA * Ntot + col0 + wn + 16 + r16] = acc01[i] + bv1;
        }
        if (rB < Mrows) {
            C[(size_t)rB * Ntot + col0 + wn + r16]      = acc10[i] + bv0;
            C[(size_t)rB * Ntot + col0 + wn + 16 + r16] = acc11[i] + bv1;
        }
    }
}

// ---------------- fused per-target online-softmax attention + aggregation ----------------
// One wave per target, 4-edge groups with prefetch; TWO independent softmax
// chains (edges i,i+1 -> chain0; i+2,i+3 -> chain1) merged at the end.
__global__ __launch_bounds__(256)
void attn_kernel(const unsigned short* __restrict__ Hs, const unsigned short* __restrict__ Ht,
                 const unsigned short* __restrict__ Hm, const float* __restrict__ attn_w,
                 const int* __restrict__ offsets, const int* __restrict__ srcs,
                 unsigned short* __restrict__ agg, int M) {
    int wave = threadIdx.x >> 6;
    int lane = threadIdx.x & 63;
    int t = blockIdx.x * 4 + wave;
    if (t >= M) return;

    int j0 = lane << 3;
    uint4 h = *(const uint4*)(Ht + (size_t)t * 512 + j0);
    f32x2 ht0 = up2(h.x), ht1 = up2(h.y), ht2 = up2(h.z), ht3 = up2(h.w);
    const float L2E = 1.4426950408889634f;
    float4 a0 = *(const float4*)(attn_w + j0);
    float4 a1 = *(const float4*)(attn_w + j0 + 4);
    f32x2 aw0 = {a0.x * L2E, a0.y * L2E};
    f32x2 aw1 = {a0.z * L2E, a0.w * L2E};
    f32x2 aw2 = {a1.x * L2E, a1.y * L2E};
    f32x2 aw3 = {a1.z * L2E, a1.w * L2E};

    int off = offsets[t];
    int end = offsets[t + 1];
    int hm_off = lane << 1;

    float m0 = -INFINITY, m1 = -INFINITY, den0 = 0.f, den1 = 0.f;
    f32x2 ac0 = {0.f, 0.f}, ac1 = {0.f, 0.f};

    int i = off;
    uint4 hA, hB, hC, hD;
    unsigned mA, mB, mC, mD;
    bool have = (end - i) >= 4;
    if (have) {
        int s0 = srcs[i], s1 = srcs[i + 1], s2 = srcs[i + 2], s3 = srcs[i + 3];
        hA = *(const uint4*)(Hs + (size_t)s0 * 512 + j0);
        hB = *(const uint4*)(Hs + (size_t)s1 * 512 + j0);
        hC = *(const uint4*)(Hs + (size_t)s2 * 512 + j0);
        hD = *(const uint4*)(Hs + (size_t)s3 * 512 + j0);
        mA = *(const unsigned*)(Hm + (size_t)s0 * 128 + hm_off);
        mB = *(const unsigned*)(Hm + (size_t)s1 * 128 + hm_off);
        mC = *(const unsigned*)(Hm + (size_t)s2 * 128 + hm_off);
        mD = *(const unsigned*)(Hm + (size_t)s3 * 128 + hm_off);
    }
    while (have) {
        int ni = i + 4;
        bool nhave = (end - ni) >= 4;
        uint4 nhA, nhB, nhC, nhD;
        unsigned nmA, nmB, nmC, nmD;
        if (nhave) {
            int s0 = srcs[ni], s1 = srcs[ni + 1], s2 = srcs[ni + 2], s3 = srcs[ni + 3];
            nhA = *(const uint4*)(Hs + (size_t)s0 * 512 + j0);
            nhB = *(const uint4*)(Hs + (size_t)s1 * 512 + j0);
            nhC = *(const uint4*)(Hs + (size_t)s2 * 512 + j0);
            nhD = *(const uint4*)(Hs + (size_t)s3 * 512 + j0);
            nmA = *(const unsigned*)(Hm + (size_t)s0 * 128 + hm_off);
            nmB = *(const unsigned*)(Hm + (size_t)s1 * 128 + hm_off);
            nmC = *(const unsigned*)(Hm + (size_t)s2 * 128 + hm_off);
            nmD = *(const unsigned*)(Hm + (size_t)s3 * 128 + hm_off);
        }

        float q0 = edge_logit(hA, ht0, ht1, ht2, ht3, aw0, aw1, aw2, aw3);
        float q1 = edge_logit(hB, ht0, ht1, ht2, ht3, aw0, aw1, aw2, aw3);
        float q2 = edge_logit(hC, ht0, ht1, ht2, ht3, aw0, aw1, aw2, aw3);
        float q3 = edge_logit(hD, ht0, ht1, ht2, ht3, aw0, aw1, aw2, aw3);
        q0 += __shfl_xor(q0, 1); q1 += __shfl_xor(q1, 1); q2 += __shfl_xor(q2, 1); q3 += __shfl_xor(q3, 1);
        q0 += __shfl_xor(q0, 2); q1 += __shfl_xor(q1, 2); q2 += __shfl_xor(q2, 2); q3 += __shfl_xor(q3, 2);
        q0 += __shfl_xor(q0, 4); q1 += __shfl_xor(q1, 4); q2 += __shfl_xor(q2, 4); q3 += __shfl_xor(q3, 4);
        q0 += __shfl_xor(q0, 8); q1 += __shfl_xor(q1, 8); q2 += __shfl_xor(q2, 8); q3 += __shfl_xor(q3, 8);

        // chain0: q0,q1
        float n0 = fmaxf(m0, fmaxf(q0, q1));
        float s0c = exp2_fast(m0 - n0);
        float p0 = exp2_fast(q0 - n0);
        float p1 = exp2_fast(q1 - n0);
        den0 = fmaf(den0, s0c, p0 + p1);
        ac0 = ac0 * s0c;
        ac0 += p0 * up2(mA);
        ac0 += p1 * up2(mB);
        m0 = n0;
        // chain1: q2,q3
        float n1 = fmaxf(m1, fmaxf(q2, q3));
        float s1c = exp2_fast(m1 - n1);
        float p2 = exp2_fast(q2 - n1);
        float p3 = exp2_fast(q3 - n1);
        den1 = fmaf(den1, s1c, p2 + p3);
        ac1 = ac1 * s1c;
        ac1 += p2 * up2(mC);
        ac1 += p3 * up2(mD);
        m1 = n1;

        i = ni;
        if (nhave) {
            hA = nhA; hB = nhB; hC = nhC; hD = nhD;
            mA = nmA; mB = nmB; mC = nmC; mD = nmD;
        }
        have = nhave;
    }
    // merge chain1 into chain0
    if (m1 != -INFINITY) {
        float mm = fmaxf(m0, m1);
        float s0c = exp2_fast(m0 - mm);
        float s1c = exp2_fast(m1 - mm);
        den0 = den0 * s0c + den1 * s1c;
        ac0 = ac0 * s0c + ac1 * s1c;
        m0 = mm;
    }
    // tail (0..3 edges) on chain0
    for (; i < end; ++i) {
        int s0 = srcs[i];
        uint4 hX = *(const uint4*)(Hs + (size_t)s0 * 512 + j0);
        unsigned mX = *(const unsigned*)(Hm + (size_t)s0 * 128 + hm_off);
        float q0 = edge_logit(hX, ht0, ht1, ht2, ht3, aw0, aw1, aw2, aw3);
        q0 += __shfl_xor(q0, 1);
        q0 += __shfl_xor(q0, 2);
        q0 += __shfl_xor(q0, 4);
        q0 += __shfl_xor(q0, 8);
        float nm = fmaxf(m0, q0);
        float sc = exp2_fast(m0 - nm);
        float p0 = exp2_fast(q0 - nm);
        den0 = fmaf(den0, sc, p0);
        ac0 = ac0 * sc + p0 * up2(mX);
        m0 = nm;
    }
    float r = (end > off) ? __builtin_amdgcn_rcpf(den0) : 0.0f;
    ushort2 o;
    o.x = f2bf(ac0.x * r);
    o.y = f2bf(ac0.y * r);
    *(ushort2*)(agg + (size_t)t * 128 + hm_off) = o;
}

extern "C" void kernel_launch(void* const* d_in, const int* in_sizes, int n_in,
                              void* d_out, int out_size, void* d_ws, size_t ws_size,
                              hipStream_t stream) {
    const float* src_f  = (const float*)d_in[0];
    const float* tgt_f  = (const float*)d_in[1];
    const int*   e_tgt  = (const int*)d_in[2];
    const int*   e_src  = (const int*)d_in[3];
    const float* Ws     = (const float*)d_in[4];
    const float* bs     = (const float*)d_in[5];
    const float* Wt     = (const float*)d_in[6];
    const float* bt     = (const float*)d_in[7];
    const float* attn_w = (const float*)d_in[8];
    const float* Wm     = (const float*)d_in[9];
    const float* bm     = (const float*)d_in[10];
    const float* Wo     = (const float*)d_in[11];
    const float* bo     = (const float*)d_in[12];

    int N = in_sizes[0] / 128;
    int M = in_sizes[1] / 128;
    int E = in_sizes[2];

    char* ws = (char*)d_ws;
    size_t woff = 0;
    auto alloc = [&](size_t bytes) -> void* {
        void* p = ws + woff;
        woff += ((bytes + 255) / 256) * 256;
        return p;
    };
    unsigned short* Hs       = (unsigned short*)alloc((size_t)N * 512 * 2);
    unsigned short* Ht       = (unsigned short*)alloc((size_t)M * 512 * 2);
    unsigned short* Hm       = (unsigned short*)alloc((size_t)N * 128 * 2);
    unsigned short* agg_bf   = (unsigned short*)alloc((size_t)M * 128 * 2);
    unsigned short* WThi     = (unsigned short*)alloc((size_t)1280 * 128 * 2);
    unsigned short* WTlo     = (unsigned short*)alloc((size_t)1280 * 128 * 2);
    float*          bias_cat = (float*)alloc(640 * 4);
    int*            counts   = (int*)alloc((size_t)2 * M * 4);   // counts | cursor
    int*            cursor   = counts + M;
    int*            offsets  = (int*)alloc((size_t)(M + 1) * 4);
    int*            srcs     = (int*)alloc((size_t)E * 4);
    int*            partials = (int*)alloc(64 * 4);
    int*            pbase    = (int*)alloc(64 * 4);

    hipMemsetAsync(counts, 0, (size_t)2 * M * 4, stream);

    const int tb = 256;
    int P = (M + 1023) / 1024;

    // CSR build
    hist_kernel<<<(E + tb - 1) / tb, tb, 0, stream>>>(e_tgt, counts, E);
    scan_partial_kernel<<<P, 256, 0, stream>>>(counts, partials, M);
    scan_partials_kernel<<<1, 64, 0, stream>>>(partials, pbase, offsets, P, M);
    scan_final_kernel<<<P, 256, 0, stream>>>(counts, pbase, offsets, M);
    scatter_kernel<<<(E + tb - 1) / tb, tb, 0, stream>>>(e_tgt, e_src, offsets, cursor, srcs, E);

    // Weight prep
    prep_weights_kernel<<<1280, 128, 0, stream>>>(Ws, Wm, Wt, Wo, bs, bm, WThi, WTlo, bias_cat);

    // Persistent-A merged hidden GEMMs (LDS-staged B)
    int nT0 = (N + 63) / 64, nT1 = (M + 63) / 64;
    gemm_hidden_kernel<<<nT0 + nT1, 256, 0, stream>>>(src_f, tgt_f, WThi, WTlo,
                                                      bias_cat, bt, Hs, Hm, Ht, N, M, nT0);

    attn_kernel<<<(M + 3) / 4, 256, 0, stream>>>(Hs, Ht, Hm, attn_w, offsets, srcs, agg_bf, M);

    // out = agg @ Wo + bo
    dim3 go(128 / 64, (M + 63) / 64);
    gemm_out_kernel<<<go, 256, 0, stream>>>(agg_bf, WThi + (size_t)1152 * 128, bo,
                                            (float*)d_out, M, 128);
}